// Round 6
// baseline (527.507 us; speedup 1.0000x reference)
//
#include <hip/hip_runtime.h>
#include <math.h>

#define NN 100000
#define NE 1600000
#define DIM 128
#define SCHUNK 1024

typedef unsigned short u16;
typedef unsigned int u32;
typedef __attribute__((ext_vector_type(8))) short bf16x8;
typedef __attribute__((ext_vector_type(4))) float f32x4;

__device__ inline u16 f2bf(float f) {
  union { float f; u32 u; } v; v.f = f;
  u32 r = v.u + 0x7FFF + ((v.u >> 16) & 1);   // round-to-nearest-even
  return (u16)(r >> 16);
}
__device__ inline float bflo(u32 u) { union { u32 u; float f; } v; v.u = u << 16; return v.f; }
__device__ inline float bfhi(u32 u) { union { u32 u; float f; } v; v.u = u & 0xFFFF0000u; return v.f; }

// ---------------- degree / norm ----------------
__global__ void k_deg(const int* __restrict__ dst, int* __restrict__ deg) {
  int i = blockIdx.x * blockDim.x + threadIdx.x;
  if (i < NE) atomicAdd(&deg[dst[i]], 1);
}

__global__ void k_dinv(const int* __restrict__ deg, float* __restrict__ dinv) {
  int i = blockIdx.x * blockDim.x + threadIdx.x;
  if (i < NN) dinv[i] = rsqrtf((float)deg[i] + 1.0f);
}

// ---------------- exclusive prefix scan of deg -> offs ----------------
__global__ void k_scan1(const int* __restrict__ deg, int* __restrict__ bsum) {
  __shared__ int sd[256];
  int t = threadIdx.x;
  int base = blockIdx.x * SCHUNK + t * 4;
  int s = 0;
#pragma unroll
  for (int j = 0; j < 4; ++j) { int idx = base + j; if (idx < NN) s += deg[idx]; }
  sd[t] = s; __syncthreads();
  for (int off = 128; off > 0; off >>= 1) {
    if (t < off) sd[t] += sd[t + off];
    __syncthreads();
  }
  if (t == 0) bsum[blockIdx.x] = sd[0];
}

__global__ void k_scan2(int* __restrict__ bsum, int nb) {
  if (threadIdx.x == 0 && blockIdx.x == 0) {
    int run = 0;
    for (int b = 0; b < nb; ++b) { int v = bsum[b]; bsum[b] = run; run += v; }
  }
}

__global__ void k_scan3(const int* __restrict__ deg, const int* __restrict__ bsum,
                        int* __restrict__ offs) {
  __shared__ int ts[256];
  int t = threadIdx.x;
  int base = blockIdx.x * SCHUNK + t * 4;
  int v[4]; int loc = 0;
#pragma unroll
  for (int j = 0; j < 4; ++j) { int idx = base + j; v[j] = (idx < NN) ? deg[idx] : 0; loc += v[j]; }
  ts[t] = loc; __syncthreads();
  for (int off = 1; off < 256; off <<= 1) {
    int x = (t >= off) ? ts[t - off] : 0;
    __syncthreads();
    ts[t] += x;
    __syncthreads();
  }
  int run = bsum[blockIdx.x] + ts[t] - loc;
#pragma unroll
  for (int j = 0; j < 4; ++j) { int idx = base + j; if (idx < NN) offs[idx] = run; run += v[j]; }
}

// fill CSR: one 8B scatter per edge: (src, eid)
__global__ void k_fill(const int* __restrict__ src, const int* __restrict__ dst,
                       const int* __restrict__ offs, int* __restrict__ cur,
                       uint2* __restrict__ csr_se) {
  int i = blockIdx.x * blockDim.x + threadIdx.x;
  if (i < NE) {
    int d = dst[i];
    int pos = offs[d] + atomicAdd(&cur[d], 1);
    csr_se[pos] = make_uint2((u32)src[i], (u32)i);
  }
}

// ---------------- fp32 -> bf16 convert (for x) ----------------
__global__ void k_tobf(const float* __restrict__ in, u16* __restrict__ out, int n4) {
  int i = blockIdx.x * blockDim.x + threadIdx.x;
  if (i < n4) {
    float4 v = ((const float4*)in)[i];
    ushort4 o;
    o.x = f2bf(v.x); o.y = f2bf(v.y); o.z = f2bf(v.z); o.w = f2bf(v.w);
    ((ushort4*)out)[i] = o;
  }
}

// ---------------- pack W (fp32 row-major [128][128]) into MFMA B-frag order ----------------
// Wp flat = ct*2048 + ks*512 + kb*128 + j*8 + b  <=  W[ks*32+kb*8+b][ct*16+j]
__global__ void k_pack(const float* __restrict__ W, u16* __restrict__ Wp) {
  int tid = blockIdx.x * blockDim.x + threadIdx.x;   // 16384
  int b = tid & 7, j = (tid >> 3) & 15, kb = (tid >> 7) & 3, ks = (tid >> 9) & 3, ct = tid >> 11;
  int k = ks * 32 + kb * 8 + b, col = ct * 16 + j;
  Wp[tid] = f2bf(W[k * 128 + col]);
}

// ---------------- MFMA GEMM: hp[n] = bf16( dinv[n] * (Xb[n] @ W) ) ----------------
__launch_bounds__(256)
__global__ void k_gemm(const u16* __restrict__ Xb, const u16* __restrict__ Wp,
                       const float* __restrict__ dinv, u16* __restrict__ hp) {
  __shared__ u16 wl[16384];        // packed W, 32 KB
  __shared__ u16 ctile[4][2048];   // per-wave epilogue staging, 16 KB
  int t = threadIdx.x;
  int w = t >> 6, l = t & 63;
  int row0 = blockIdx.x * 64;
  int rbase = row0 + w * 16;

#pragma unroll
  for (int i = 0; i < 8; ++i) {
    int off = (i * 256 + t) * 8;
    *(uint4*)&wl[off] = *(const uint4*)&Wp[off];
  }
  __syncthreads();

  int arow = rbase + (l & 15);
  arow = arow < NN ? arow : NN - 1;
  const u16* abase = Xb + (size_t)arow * DIM + (l >> 4) * 8;
  bf16x8 a[4];
#pragma unroll
  for (int ks = 0; ks < 4; ++ks) a[ks] = *(const bf16x8*)(abase + ks * 32);

  f32x4 acc[8];
#pragma unroll
  for (int ct = 0; ct < 8; ++ct) {
    acc[ct] = (f32x4){0.f, 0.f, 0.f, 0.f};
#pragma unroll
    for (int ks = 0; ks < 4; ++ks) {
      bf16x8 bfr = *(const bf16x8*)&wl[ct * 2048 + ks * 512 + (l >> 4) * 128 + (l & 15) * 8];
      acc[ct] = __builtin_amdgcn_mfma_f32_16x16x32_bf16(a[ks], bfr, acc[ct], 0, 0, 0);
    }
  }

  float dv[4];
#pragma unroll
  for (int v = 0; v < 4; ++v) {
    int rr = rbase + (l >> 4) * 4 + v;
    dv[v] = dinv[rr < NN ? rr : NN - 1];
  }
  u16* ct_lds = ctile[w];
#pragma unroll
  for (int ct = 0; ct < 8; ++ct) {
#pragma unroll
    for (int v = 0; v < 4; ++v) {
      int row = (l >> 4) * 4 + v;
      ct_lds[row * DIM + ct * 16 + (l & 15)] = f2bf(dv[v] * acc[ct][v]);
    }
  }
  __syncthreads();
#pragma unroll
  for (int rr = 0; rr < 4; ++rr) {
    int row = rr * 4 + (l >> 4);
    int grow = rbase + row;
    if (grow < NN)
      *(uint4*)&hp[(size_t)grow * DIM + (l & 15) * 8] =
          *(const uint4*)&ct_lds[row * DIM + (l & 15) * 8];
  }
}

// ---------------- aggregation on bf16 h': out = bf16( dn*(sum h'[u] + h'[n]) + b ) ----
__launch_bounds__(256)
__global__ void k_agg(const u16* __restrict__ hp, const uint2* __restrict__ csr_se,
                      const int* __restrict__ offs, const int* __restrict__ deg,
                      const float* __restrict__ dinv, const float* __restrict__ bias,
                      u16* __restrict__ outb, int relu) {
  int t = threadIdx.x;
  int g = t >> 5, l = t & 31;
  int n = blockIdx.x * 8 + g;          // NN/8 exact
  float dn = dinv[n];
  int s = offs[n], cnt = deg[n];
  const uint2* hp2 = (const uint2*)hp;   // 4 bf16 per uint2, 32 per row
  float a0 = 0.f, a1 = 0.f, a2 = 0.f, a3 = 0.f;
  int i = 0;
  for (; i + 4 <= cnt; i += 4) {
    int u0 = csr_se[s + i].x;
    int u1 = csr_se[s + i + 1].x;
    int u2 = csr_se[s + i + 2].x;
    int u3 = csr_se[s + i + 3].x;
    uint2 v0 = hp2[(size_t)u0 * 32 + l];
    uint2 v1 = hp2[(size_t)u1 * 32 + l];
    uint2 v2 = hp2[(size_t)u2 * 32 + l];
    uint2 v3 = hp2[(size_t)u3 * 32 + l];
    a0 += (bflo(v0.x) + bflo(v1.x)) + (bflo(v2.x) + bflo(v3.x));
    a1 += (bfhi(v0.x) + bfhi(v1.x)) + (bfhi(v2.x) + bfhi(v3.x));
    a2 += (bflo(v0.y) + bflo(v1.y)) + (bflo(v2.y) + bflo(v3.y));
    a3 += (bfhi(v0.y) + bfhi(v1.y)) + (bfhi(v2.y) + bfhi(v3.y));
  }
  for (; i < cnt; ++i) {
    int u = csr_se[s + i].x;
    uint2 v = hp2[(size_t)u * 32 + l];
    a0 += bflo(v.x); a1 += bfhi(v.x); a2 += bflo(v.y); a3 += bfhi(v.y);
  }
  uint2 sv = hp2[(size_t)n * 32 + l];
  float4 bb = ((const float4*)bias)[l];
  float r0 = dn * (a0 + bflo(sv.x)) + bb.x;
  float r1 = dn * (a1 + bfhi(sv.x)) + bb.y;
  float r2 = dn * (a2 + bflo(sv.y)) + bb.z;
  float r3 = dn * (a3 + bfhi(sv.y)) + bb.w;
  if (relu) {
    r0 = fmaxf(r0, 0.f); r1 = fmaxf(r1, 0.f);
    r2 = fmaxf(r2, 0.f); r3 = fmaxf(r3, 0.f);
  }
  ushort4 o; o.x = f2bf(r0); o.y = f2bf(r1); o.z = f2bf(r2); o.w = f2bf(r3);
  *(ushort4*)&outb[(size_t)n * DIM + l * 4] = o;
}

// ---------------- decode per-node: dst row in regs, gather src rows only ----------------
__device__ inline float sigm(float x) { return 1.0f / (1.0f + expf(-x)); }

__launch_bounds__(256)
__global__ void k_decode_node(const u16* __restrict__ z, const uint2* __restrict__ csr_se,
                              const int* __restrict__ offs, const int* __restrict__ deg,
                              float* __restrict__ out) {
  int t = threadIdx.x;
  int g = t >> 5, l = t & 31;
  int n = blockIdx.x * 8 + g;          // NN/8 exact
  const uint2* z2 = (const uint2*)z;   // 4 bf16 per uint2, 32 per row
  uint2 zn = z2[(size_t)n * 32 + l];
  float n0 = bflo(zn.x), n1 = bfhi(zn.x), n2 = bflo(zn.y), n3 = bfhi(zn.y);
  int s = offs[n], cnt = deg[n];
  int i = 0;
  for (; i + 4 <= cnt; i += 4) {
    uint2 e0 = csr_se[s + i];
    uint2 e1 = csr_se[s + i + 1];
    uint2 e2 = csr_se[s + i + 2];
    uint2 e3 = csr_se[s + i + 3];
    uint2 v0 = z2[(size_t)e0.x * 32 + l];
    uint2 v1 = z2[(size_t)e1.x * 32 + l];
    uint2 v2 = z2[(size_t)e2.x * 32 + l];
    uint2 v3 = z2[(size_t)e3.x * 32 + l];
    float p0 = bflo(v0.x) * n0 + bfhi(v0.x) * n1 + bflo(v0.y) * n2 + bfhi(v0.y) * n3;
    float p1 = bflo(v1.x) * n0 + bfhi(v1.x) * n1 + bflo(v1.y) * n2 + bfhi(v1.y) * n3;
    float p2 = bflo(v2.x) * n0 + bfhi(v2.x) * n1 + bflo(v2.y) * n2 + bfhi(v2.y) * n3;
    float p3 = bflo(v3.x) * n0 + bfhi(v3.x) * n1 + bflo(v3.y) * n2 + bfhi(v3.y) * n3;
#pragma unroll
    for (int off = 16; off >= 1; off >>= 1) {
      p0 += __shfl_xor(p0, off);
      p1 += __shfl_xor(p1, off);
      p2 += __shfl_xor(p2, off);
      p3 += __shfl_xor(p3, off);
    }
    if (l == 0) {
      out[e0.y] = sigm(p0);
      out[e1.y] = sigm(p1);
      out[e2.y] = sigm(p2);
      out[e3.y] = sigm(p3);
    }
  }
  for (; i < cnt; ++i) {
    uint2 e = csr_se[s + i];
    uint2 v = z2[(size_t)e.x * 32 + l];
    float p = bflo(v.x) * n0 + bfhi(v.x) * n1 + bflo(v.y) * n2 + bfhi(v.y) * n3;
#pragma unroll
    for (int off = 16; off >= 1; off >>= 1) p += __shfl_xor(p, off);
    if (l == 0) out[e.y] = sigm(p);
  }
}

extern "C" void kernel_launch(void* const* d_in, const int* in_sizes, int n_in,
                              void* d_out, int out_size, void* d_ws, size_t ws_size,
                              hipStream_t stream) {
  const float* x  = (const float*)d_in[0];
  const float* W1 = (const float*)d_in[1];
  const float* b1 = (const float*)d_in[2];
  const float* W2 = (const float*)d_in[3];
  const float* b2 = (const float*)d_in[4];
  const float* W3 = (const float*)d_in[5];
  const float* b3 = (const float*)d_in[6];
  const int*   ei = (const int*)d_in[7];
  const int* src = ei;
  const int* dst = ei + NE;
  float* out = (float*)d_out;

  char* w = (char*)d_ws;
  size_t p = 0;
  auto alloc = [&](size_t bytes) -> void* {
    void* r = w + p;
    p += (bytes + 255) & ~(size_t)255;
    return r;
  };
  int*   deg     = (int*)alloc((size_t)NN * 4);
  int*   cur     = (int*)alloc((size_t)NN * 4);
  int*   offs    = (int*)alloc((size_t)NN * 4);
  float* dinv    = (float*)alloc((size_t)NN * 4);
  int*   bsum    = (int*)alloc(1024);
  uint2* csr_se  = (uint2*)alloc((size_t)NE * 8);       // (src, eid) per slot
  u16*   Xb      = (u16*)alloc((size_t)NN * DIM * 2);   // bf16 input features
  u16*   hp      = (u16*)alloc((size_t)NN * DIM * 2);   // bf16 GEMM out (premult by dinv)
  u16*   hb      = (u16*)alloc((size_t)NN * DIM * 2);   // bf16 agg out (next GEMM input / z)
  u16*   Wp1     = (u16*)alloc(16384 * 2);
  u16*   Wp2     = (u16*)alloc(16384 * 2);
  u16*   Wp3     = (u16*)alloc(16384 * 2);
  (void)in_sizes; (void)n_in; (void)out_size; (void)ws_size;

  hipMemsetAsync(deg, 0, (size_t)NN * 4, stream);
  hipMemsetAsync(cur, 0, (size_t)NN * 4, stream);

  k_deg<<<(NE + 255) / 256, 256, 0, stream>>>(dst, deg);
  k_dinv<<<(NN + 255) / 256, 256, 0, stream>>>(deg, dinv);
  int nb = (NN + SCHUNK - 1) / SCHUNK;  // 98
  k_scan1<<<nb, 256, 0, stream>>>(deg, bsum);
  k_scan2<<<1, 64, 0, stream>>>(bsum, nb);
  k_scan3<<<nb, 256, 0, stream>>>(deg, bsum, offs);
  k_fill<<<(NE + 255) / 256, 256, 0, stream>>>(src, dst, offs, cur, csr_se);

  k_tobf<<<(NN * DIM / 4 + 255) / 256, 256, 0, stream>>>(x, Xb, NN * DIM / 4);
  k_pack<<<64, 256, 0, stream>>>(W1, Wp1);
  k_pack<<<64, 256, 0, stream>>>(W2, Wp2);
  k_pack<<<64, 256, 0, stream>>>(W3, Wp3);

  int gb = (NN + 63) / 64;  // 1563
  k_gemm<<<gb, 256, 0, stream>>>(Xb, Wp1, dinv, hp);
  k_agg <<<NN / 8, 256, 0, stream>>>(hp, csr_se, offs, deg, dinv, b1, hb, 1);
  k_gemm<<<gb, 256, 0, stream>>>(hb, Wp2, dinv, hp);
  k_agg <<<NN / 8, 256, 0, stream>>>(hp, csr_se, offs, deg, dinv, b2, hb, 1);
  k_gemm<<<gb, 256, 0, stream>>>(hb, Wp3, dinv, hp);
  k_agg <<<NN / 8, 256, 0, stream>>>(hp, csr_se, offs, deg, dinv, b3, hb, 0);

  k_decode_node<<<NN / 8, 256, 0, stream>>>(hb, csr_se, offs, deg, out);
}

// Round 7
// 475.279 us; speedup vs baseline: 1.1099x; 1.1099x over previous
//
#include <hip/hip_runtime.h>
#include <math.h>

#define NN 100000
#define NE 1600000
#define DIM 128
#define SCHUNK 1024
#define NBK 391        // ceil(NN/256) buckets of 256 nodes
#define ECH 4096       // edges per k_bucket block

typedef unsigned short u16;
typedef unsigned int u32;
typedef __attribute__((ext_vector_type(8))) short bf16x8;
typedef __attribute__((ext_vector_type(4))) float f32x4;

__device__ inline u16 f2bf(float f) {
  union { float f; u32 u; } v; v.f = f;
  u32 r = v.u + 0x7FFF + ((v.u >> 16) & 1);   // round-to-nearest-even
  return (u16)(r >> 16);
}
__device__ inline float bflo(u32 u) { union { u32 u; float f; } v; v.u = u << 16; return v.f; }
__device__ inline float bfhi(u32 u) { union { u32 u; float f; } v; v.u = u & 0xFFFF0000u; return v.f; }

// ---------------- degree / norm ----------------
__global__ void k_deg(const int* __restrict__ dst, int* __restrict__ deg) {
  int i = blockIdx.x * blockDim.x + threadIdx.x;
  if (i < NE) atomicAdd(&deg[dst[i]], 1);
}

__global__ void k_dinv(const int* __restrict__ deg, float* __restrict__ dinv) {
  int i = blockIdx.x * blockDim.x + threadIdx.x;
  if (i < NN) dinv[i] = rsqrtf((float)deg[i] + 1.0f);
}

// ---------------- exclusive prefix scan of deg -> offs ----------------
__global__ void k_scan1(const int* __restrict__ deg, int* __restrict__ bsum) {
  __shared__ int sd[256];
  int t = threadIdx.x;
  int base = blockIdx.x * SCHUNK + t * 4;
  int s = 0;
#pragma unroll
  for (int j = 0; j < 4; ++j) { int idx = base + j; if (idx < NN) s += deg[idx]; }
  sd[t] = s; __syncthreads();
  for (int off = 128; off > 0; off >>= 1) {
    if (t < off) sd[t] += sd[t + off];
    __syncthreads();
  }
  if (t == 0) bsum[blockIdx.x] = sd[0];
}

__global__ void k_scan2(int* __restrict__ bsum, int nb) {
  if (threadIdx.x == 0 && blockIdx.x == 0) {
    int run = 0;
    for (int b = 0; b < nb; ++b) { int v = bsum[b]; bsum[b] = run; run += v; }
  }
}

__global__ void k_scan3(const int* __restrict__ deg, const int* __restrict__ bsum,
                        int* __restrict__ offs) {
  __shared__ int ts[256];
  int t = threadIdx.x;
  int base = blockIdx.x * SCHUNK + t * 4;
  int v[4]; int loc = 0;
#pragma unroll
  for (int j = 0; j < 4; ++j) { int idx = base + j; v[j] = (idx < NN) ? deg[idx] : 0; loc += v[j]; }
  ts[t] = loc; __syncthreads();
  for (int off = 1; off < 256; off <<= 1) {
    int x = (t >= off) ? ts[t - off] : 0;
    __syncthreads();
    ts[t] += x;
    __syncthreads();
  }
  int run = bsum[blockIdx.x] + ts[t] - loc;
#pragma unroll
  for (int j = 0; j < 4; ++j) { int idx = base + j; if (idx < NN) offs[idx] = run; run += v[j]; }
}

// ---------------- bucket pass: bin edges by dst>>8 into staging (locality) ----------------
// staging entry: (src, (dst&255)<<21 | eid); bucket b's staging region starts at offs[b*256]
__launch_bounds__(256)
__global__ void k_bucket(const int* __restrict__ src, const int* __restrict__ dst,
                         const int* __restrict__ offs, int* __restrict__ bcur,
                         uint2* __restrict__ bstage) {
  __shared__ int cnt[512];
  __shared__ int bl[512];
  __shared__ int gb[512];
  __shared__ int tmp[256];
  __shared__ uint2 st[ECH];
  int t = threadIdx.x;
  int e0 = blockIdx.x * ECH;
  cnt[t] = 0; cnt[t + 256] = 0;
  __syncthreads();
  int b_[16], r_[16]; u32 s_[16], y_[16];
#pragma unroll
  for (int k = 0; k < 16; ++k) {
    int i = e0 + k * 256 + t;
    b_[k] = -1;
    if (i < NE) {
      int d = dst[i];
      int bb = d >> 8;
      b_[k] = bb;
      s_[k] = (u32)src[i];
      y_[k] = ((u32)(d & 255) << 21) | (u32)i;
      r_[k] = atomicAdd(&cnt[bb], 1);
    }
  }
  __syncthreads();
  int c0 = cnt[2 * t], c1 = cnt[2 * t + 1];
  tmp[t] = c0 + c1;
  __syncthreads();
  for (int off = 1; off < 256; off <<= 1) {
    int v = (t >= off) ? tmp[t - off] : 0;
    __syncthreads();
    tmp[t] += v;
    __syncthreads();
  }
  int excl = tmp[t] - (c0 + c1);
  bl[2 * t] = excl; bl[2 * t + 1] = excl + c0;
  __syncthreads();
#pragma unroll
  for (int k = 0; k < 16; ++k)
    if (b_[k] >= 0) st[bl[b_[k]] + r_[k]] = make_uint2(s_[k], y_[k]);
  for (int b = t; b < 512; b += 256) {
    int n = cnt[b];
    gb[b] = (n > 0) ? atomicAdd(&bcur[b], n) : 0;
  }
  __syncthreads();
  for (int b = t; b < 512; b += 256) {
    int n = cnt[b];
    if (n > 0) {
      uint2* dp = bstage + offs[b << 8] + gb[b];
      const uint2* sp = st + bl[b];
      for (int j = 0; j < n; ++j) dp[j] = sp[j];
    }
  }
}

// ---------------- final fill: one block per bucket, L2-local CSR window ----------------
__launch_bounds__(256)
__global__ void k_fillb(const uint2* __restrict__ bstage, const int* __restrict__ offs,
                        int* __restrict__ csr_src, int* __restrict__ csr_eid) {
  __shared__ int curl[256];
  int t = threadIdx.x;
  int b = blockIdx.x;                  // 0..NBK-1
  int nb0 = b << 8;
  curl[t] = 0;
  __syncthreads();
  int sbase = offs[nb0];
  int send = (b == NBK - 1) ? NE : offs[nb0 + 256];
  for (int j = sbase + t; j < send; j += 256) {
    uint2 e = bstage[j];
    int dl = e.y >> 21;
    int eid = e.y & 0x1FFFFF;
    int pos = offs[nb0 + dl] + atomicAdd(&curl[dl], 1);
    csr_src[pos] = (int)e.x;
    csr_eid[pos] = eid;
  }
}

// ---------------- fp32 -> bf16 convert (for x) ----------------
__global__ void k_tobf(const float* __restrict__ in, u16* __restrict__ out, int n4) {
  int i = blockIdx.x * blockDim.x + threadIdx.x;
  if (i < n4) {
    float4 v = ((const float4*)in)[i];
    ushort4 o;
    o.x = f2bf(v.x); o.y = f2bf(v.y); o.z = f2bf(v.z); o.w = f2bf(v.w);
    ((ushort4*)out)[i] = o;
  }
}

// ---------------- pack W (fp32 row-major [128][128]) into MFMA B-frag order ----------------
__global__ void k_pack(const float* __restrict__ W, u16* __restrict__ Wp) {
  int tid = blockIdx.x * blockDim.x + threadIdx.x;   // 16384
  int b = tid & 7, j = (tid >> 3) & 15, kb = (tid >> 7) & 3, ks = (tid >> 9) & 3, ct = tid >> 11;
  int k = ks * 32 + kb * 8 + b, col = ct * 16 + j;
  Wp[tid] = f2bf(W[k * 128 + col]);
}

// ---------------- MFMA GEMM: hp[n] = bf16( dinv[n] * (Xb[n] @ W) ) ----------------
__launch_bounds__(256)
__global__ void k_gemm(const u16* __restrict__ Xb, const u16* __restrict__ Wp,
                       const float* __restrict__ dinv, u16* __restrict__ hp) {
  __shared__ u16 wl[16384];        // packed W, 32 KB
  __shared__ u16 ctile[4][2048];   // per-wave epilogue staging, 16 KB
  int t = threadIdx.x;
  int w = t >> 6, l = t & 63;
  int row0 = blockIdx.x * 64;
  int rbase = row0 + w * 16;

#pragma unroll
  for (int i = 0; i < 8; ++i) {
    int off = (i * 256 + t) * 8;
    *(uint4*)&wl[off] = *(const uint4*)&Wp[off];
  }
  __syncthreads();

  int arow = rbase + (l & 15);
  arow = arow < NN ? arow : NN - 1;
  const u16* abase = Xb + (size_t)arow * DIM + (l >> 4) * 8;
  bf16x8 a[4];
#pragma unroll
  for (int ks = 0; ks < 4; ++ks) a[ks] = *(const bf16x8*)(abase + ks * 32);

  f32x4 acc[8];
#pragma unroll
  for (int ct = 0; ct < 8; ++ct) {
    acc[ct] = (f32x4){0.f, 0.f, 0.f, 0.f};
#pragma unroll
    for (int ks = 0; ks < 4; ++ks) {
      bf16x8 bfr = *(const bf16x8*)&wl[ct * 2048 + ks * 512 + (l >> 4) * 128 + (l & 15) * 8];
      acc[ct] = __builtin_amdgcn_mfma_f32_16x16x32_bf16(a[ks], bfr, acc[ct], 0, 0, 0);
    }
  }

  float dv[4];
#pragma unroll
  for (int v = 0; v < 4; ++v) {
    int rr = rbase + (l >> 4) * 4 + v;
    dv[v] = dinv[rr < NN ? rr : NN - 1];
  }
  u16* ct_lds = ctile[w];
#pragma unroll
  for (int ct = 0; ct < 8; ++ct) {
#pragma unroll
    for (int v = 0; v < 4; ++v) {
      int row = (l >> 4) * 4 + v;
      ct_lds[row * DIM + ct * 16 + (l & 15)] = f2bf(dv[v] * acc[ct][v]);
    }
  }
  __syncthreads();
#pragma unroll
  for (int rr = 0; rr < 4; ++rr) {
    int row = rr * 4 + (l >> 4);
    int grow = rbase + row;
    if (grow < NN)
      *(uint4*)&hp[(size_t)grow * DIM + (l & 15) * 8] =
          *(const uint4*)&ct_lds[row * DIM + (l & 15) * 8];
  }
}

// ---------------- aggregation on bf16 h': out = bf16( dn*(sum h'[u] + h'[n]) + b ) ----
__launch_bounds__(256)
__global__ void k_agg(const u16* __restrict__ hp, const int* __restrict__ csr_src,
                      const int* __restrict__ offs, const int* __restrict__ deg,
                      const float* __restrict__ dinv, const float* __restrict__ bias,
                      u16* __restrict__ outb, int relu) {
  int t = threadIdx.x;
  int g = t >> 5, l = t & 31;
  int n = blockIdx.x * 8 + g;          // NN/8 exact
  float dn = dinv[n];
  int s = offs[n], cnt = deg[n];
  const uint2* hp2 = (const uint2*)hp;   // 4 bf16 per uint2, 32 per row
  float a0 = 0.f, a1 = 0.f, a2 = 0.f, a3 = 0.f;
  int i = 0;
  for (; i + 4 <= cnt; i += 4) {
    int u0 = csr_src[s + i];
    int u1 = csr_src[s + i + 1];
    int u2 = csr_src[s + i + 2];
    int u3 = csr_src[s + i + 3];
    uint2 v0 = hp2[(size_t)u0 * 32 + l];
    uint2 v1 = hp2[(size_t)u1 * 32 + l];
    uint2 v2 = hp2[(size_t)u2 * 32 + l];
    uint2 v3 = hp2[(size_t)u3 * 32 + l];
    a0 += (bflo(v0.x) + bflo(v1.x)) + (bflo(v2.x) + bflo(v3.x));
    a1 += (bfhi(v0.x) + bfhi(v1.x)) + (bfhi(v2.x) + bfhi(v3.x));
    a2 += (bflo(v0.y) + bflo(v1.y)) + (bflo(v2.y) + bflo(v3.y));
    a3 += (bfhi(v0.y) + bfhi(v1.y)) + (bfhi(v2.y) + bfhi(v3.y));
  }
  for (; i < cnt; ++i) {
    int u = csr_src[s + i];
    uint2 v = hp2[(size_t)u * 32 + l];
    a0 += bflo(v.x); a1 += bfhi(v.x); a2 += bflo(v.y); a3 += bfhi(v.y);
  }
  uint2 sv = hp2[(size_t)n * 32 + l];
  float4 bb = ((const float4*)bias)[l];
  float r0 = dn * (a0 + bflo(sv.x)) + bb.x;
  float r1 = dn * (a1 + bfhi(sv.x)) + bb.y;
  float r2 = dn * (a2 + bflo(sv.y)) + bb.z;
  float r3 = dn * (a3 + bfhi(sv.y)) + bb.w;
  if (relu) {
    r0 = fmaxf(r0, 0.f); r1 = fmaxf(r1, 0.f);
    r2 = fmaxf(r2, 0.f); r3 = fmaxf(r3, 0.f);
  }
  ushort4 o; o.x = f2bf(r0); o.y = f2bf(r1); o.z = f2bf(r2); o.w = f2bf(r3);
  *(ushort4*)&outb[(size_t)n * DIM + l * 4] = o;
}

// ---------------- decode per-node: dst row in regs, gather src rows only ----------------
__device__ inline float sigm(float x) { return 1.0f / (1.0f + expf(-x)); }

__launch_bounds__(256)
__global__ void k_decode_node(const u16* __restrict__ z, const int* __restrict__ csr_src,
                              const int* __restrict__ csr_eid, const int* __restrict__ offs,
                              const int* __restrict__ deg, float* __restrict__ out) {
  int t = threadIdx.x;
  int g = t >> 5, l = t & 31;
  int n = blockIdx.x * 8 + g;          // NN/8 exact
  const uint2* z2 = (const uint2*)z;   // 4 bf16 per uint2, 32 per row
  uint2 zn = z2[(size_t)n * 32 + l];
  float n0 = bflo(zn.x), n1 = bfhi(zn.x), n2 = bflo(zn.y), n3 = bfhi(zn.y);
  int s = offs[n], cnt = deg[n];
  int i = 0;
  for (; i + 4 <= cnt; i += 4) {
    int u0 = csr_src[s + i];
    int u1 = csr_src[s + i + 1];
    int u2 = csr_src[s + i + 2];
    int u3 = csr_src[s + i + 3];
    uint2 v0 = z2[(size_t)u0 * 32 + l];
    uint2 v1 = z2[(size_t)u1 * 32 + l];
    uint2 v2 = z2[(size_t)u2 * 32 + l];
    uint2 v3 = z2[(size_t)u3 * 32 + l];
    float p0 = bflo(v0.x) * n0 + bfhi(v0.x) * n1 + bflo(v0.y) * n2 + bfhi(v0.y) * n3;
    float p1 = bflo(v1.x) * n0 + bfhi(v1.x) * n1 + bflo(v1.y) * n2 + bfhi(v1.y) * n3;
    float p2 = bflo(v2.x) * n0 + bfhi(v2.x) * n1 + bflo(v2.y) * n2 + bfhi(v2.y) * n3;
    float p3 = bflo(v3.x) * n0 + bfhi(v3.x) * n1 + bflo(v3.y) * n2 + bfhi(v3.y) * n3;
#pragma unroll
    for (int off = 16; off >= 1; off >>= 1) {
      p0 += __shfl_xor(p0, off);
      p1 += __shfl_xor(p1, off);
      p2 += __shfl_xor(p2, off);
      p3 += __shfl_xor(p3, off);
    }
    if (l == 0) {
      out[csr_eid[s + i]]     = sigm(p0);
      out[csr_eid[s + i + 1]] = sigm(p1);
      out[csr_eid[s + i + 2]] = sigm(p2);
      out[csr_eid[s + i + 3]] = sigm(p3);
    }
  }
  for (; i < cnt; ++i) {
    int u = csr_src[s + i];
    uint2 v = z2[(size_t)u * 32 + l];
    float p = bflo(v.x) * n0 + bfhi(v.x) * n1 + bflo(v.y) * n2 + bfhi(v.y) * n3;
#pragma unroll
    for (int off = 16; off >= 1; off >>= 1) p += __shfl_xor(p, off);
    if (l == 0) out[csr_eid[s + i]] = sigm(p);
  }
}

extern "C" void kernel_launch(void* const* d_in, const int* in_sizes, int n_in,
                              void* d_out, int out_size, void* d_ws, size_t ws_size,
                              hipStream_t stream) {
  const float* x  = (const float*)d_in[0];
  const float* W1 = (const float*)d_in[1];
  const float* b1 = (const float*)d_in[2];
  const float* W2 = (const float*)d_in[3];
  const float* b2 = (const float*)d_in[4];
  const float* W3 = (const float*)d_in[5];
  const float* b3 = (const float*)d_in[6];
  const int*   ei = (const int*)d_in[7];
  const int* src = ei;
  const int* dst = ei + NE;
  float* out = (float*)d_out;

  char* w = (char*)d_ws;
  size_t p = 0;
  auto alloc = [&](size_t bytes) -> void* {
    void* r = w + p;
    p += (bytes + 255) & ~(size_t)255;
    return r;
  };
  int*   deg     = (int*)alloc((size_t)NN * 4);
  int*   offs    = (int*)alloc((size_t)NN * 4);
  float* dinv    = (float*)alloc((size_t)NN * 4);
  int*   bsum    = (int*)alloc(1024);
  int*   bcur    = (int*)alloc(512 * 4);
  uint2* bstage  = (uint2*)alloc((size_t)NE * 8);       // bucketed staging
  int*   csr_src = (int*)alloc((size_t)NE * 4);
  int*   csr_eid = (int*)alloc((size_t)NE * 4);
  u16*   Xb      = (u16*)alloc((size_t)NN * DIM * 2);   // bf16 input features
  u16*   hp      = (u16*)alloc((size_t)NN * DIM * 2);   // bf16 GEMM out (premult by dinv)
  u16*   hb      = (u16*)alloc((size_t)NN * DIM * 2);   // bf16 agg out (next GEMM input / z)
  u16*   Wp1     = (u16*)alloc(16384 * 2);
  u16*   Wp2     = (u16*)alloc(16384 * 2);
  u16*   Wp3     = (u16*)alloc(16384 * 2);
  (void)in_sizes; (void)n_in; (void)out_size; (void)ws_size;

  hipMemsetAsync(deg, 0, (size_t)NN * 4, stream);
  hipMemsetAsync(bcur, 0, 512 * 4, stream);

  k_deg<<<(NE + 255) / 256, 256, 0, stream>>>(dst, deg);
  k_dinv<<<(NN + 255) / 256, 256, 0, stream>>>(deg, dinv);
  int nb = (NN + SCHUNK - 1) / SCHUNK;  // 98
  k_scan1<<<nb, 256, 0, stream>>>(deg, bsum);
  k_scan2<<<1, 64, 0, stream>>>(bsum, nb);
  k_scan3<<<nb, 256, 0, stream>>>(deg, bsum, offs);

  int cb = (NE + ECH - 1) / ECH;  // 391
  k_bucket<<<cb, 256, 0, stream>>>(src, dst, offs, bcur, bstage);
  k_fillb<<<NBK, 256, 0, stream>>>(bstage, offs, csr_src, csr_eid);

  k_tobf<<<(NN * DIM / 4 + 255) / 256, 256, 0, stream>>>(x, Xb, NN * DIM / 4);
  k_pack<<<64, 256, 0, stream>>>(W1, Wp1);
  k_pack<<<64, 256, 0, stream>>>(W2, Wp2);
  k_pack<<<64, 256, 0, stream>>>(W3, Wp3);

  int gb = (NN + 63) / 64;  // 1563
  k_gemm<<<gb, 256, 0, stream>>>(Xb, Wp1, dinv, hp);
  k_agg <<<NN / 8, 256, 0, stream>>>(hp, csr_src, offs, deg, dinv, b1, hb, 1);
  k_gemm<<<gb, 256, 0, stream>>>(hb, Wp2, dinv, hp);
  k_agg <<<NN / 8, 256, 0, stream>>>(hp, csr_src, offs, deg, dinv, b2, hb, 1);
  k_gemm<<<gb, 256, 0, stream>>>(hb, Wp3, dinv, hp);
  k_agg <<<NN / 8, 256, 0, stream>>>(hp, csr_src, offs, deg, dinv, b3, hb, 0);

  k_decode_node<<<NN / 8, 256, 0, stream>>>(hb, csr_src, csr_eid, offs, deg, out);
}

// Round 8
// 461.038 us; speedup vs baseline: 1.1442x; 1.0309x over previous
//
#include <hip/hip_runtime.h>
#include <math.h>

#define NN 100000
#define NE 1600000
#define DIM 128
#define SCHUNK 1024
#define NBK 391        // ceil(NN/256) buckets of 256 nodes
#define ECH 4096       // edges per k_bucket block

typedef unsigned short u16;
typedef unsigned int u32;
typedef __attribute__((ext_vector_type(8))) short bf16x8;
typedef __attribute__((ext_vector_type(4))) float f32x4;

__device__ inline u16 f2bf(float f) {
  union { float f; u32 u; } v; v.f = f;
  u32 r = v.u + 0x7FFF + ((v.u >> 16) & 1);   // round-to-nearest-even
  return (u16)(r >> 16);
}
__device__ inline float bflo(u32 u) { union { u32 u; float f; } v; v.u = u << 16; return v.f; }
__device__ inline float bfhi(u32 u) { union { u32 u; float f; } v; v.u = u & 0xFFFF0000u; return v.f; }
__device__ inline float sigm(float x) { return 1.0f / (1.0f + expf(-x)); }

// ---------------- degree ----------------
__global__ void k_deg(const int* __restrict__ dst, int* __restrict__ deg) {
  int i = blockIdx.x * blockDim.x + threadIdx.x;
  if (i < NE) atomicAdd(&deg[dst[i]], 1);
}

// ---------------- exclusive prefix scan of deg -> offs (+ dinv fused in scan3) --------
__global__ void k_scan1(const int* __restrict__ deg, int* __restrict__ bsum) {
  __shared__ int sd[256];
  int t = threadIdx.x;
  int base = blockIdx.x * SCHUNK + t * 4;
  int s = 0;
#pragma unroll
  for (int j = 0; j < 4; ++j) { int idx = base + j; if (idx < NN) s += deg[idx]; }
  sd[t] = s; __syncthreads();
  for (int off = 128; off > 0; off >>= 1) {
    if (t < off) sd[t] += sd[t + off];
    __syncthreads();
  }
  if (t == 0) bsum[blockIdx.x] = sd[0];
}

__global__ void k_scan2(int* __restrict__ bsum, int nb) {   // nb <= 128, 1 block of 128
  __shared__ int sd[128];
  int t = threadIdx.x;
  int v = (t < nb) ? bsum[t] : 0;
  sd[t] = v; __syncthreads();
  for (int off = 1; off < 128; off <<= 1) {
    int x = (t >= off) ? sd[t - off] : 0;
    __syncthreads();
    sd[t] += x;
    __syncthreads();
  }
  if (t < nb) bsum[t] = sd[t] - v;
}

__global__ void k_scan3(const int* __restrict__ deg, const int* __restrict__ bsum,
                        int* __restrict__ offs, float* __restrict__ dinv) {
  __shared__ int ts[256];
  int t = threadIdx.x;
  int base = blockIdx.x * SCHUNK + t * 4;
  int v[4]; int loc = 0;
#pragma unroll
  for (int j = 0; j < 4; ++j) { int idx = base + j; v[j] = (idx < NN) ? deg[idx] : 0; loc += v[j]; }
  ts[t] = loc; __syncthreads();
  for (int off = 1; off < 256; off <<= 1) {
    int x = (t >= off) ? ts[t - off] : 0;
    __syncthreads();
    ts[t] += x;
    __syncthreads();
  }
  int run = bsum[blockIdx.x] + ts[t] - loc;
#pragma unroll
  for (int j = 0; j < 4; ++j) {
    int idx = base + j;
    if (idx < NN) {
      offs[idx] = run;
      dinv[idx] = rsqrtf((float)v[j] + 1.0f);
    }
    run += v[j];
  }
}

// ---------------- bucket pass: bin edges by dst>>8 into staging (locality) ----------------
__launch_bounds__(256)
__global__ void k_bucket(const int* __restrict__ src, const int* __restrict__ dst,
                         const int* __restrict__ offs, int* __restrict__ bcur,
                         uint2* __restrict__ bstage) {
  __shared__ int cnt[512];
  __shared__ int bl[512];
  __shared__ int gb[512];
  __shared__ int tmp[256];
  __shared__ uint2 st[ECH];
  int t = threadIdx.x;
  int e0 = blockIdx.x * ECH;
  cnt[t] = 0; cnt[t + 256] = 0;
  __syncthreads();
  int b_[16], r_[16]; u32 s_[16], y_[16];
#pragma unroll
  for (int k = 0; k < 16; ++k) {
    int i = e0 + k * 256 + t;
    b_[k] = -1;
    if (i < NE) {
      int d = dst[i];
      int bb = d >> 8;
      b_[k] = bb;
      s_[k] = (u32)src[i];
      y_[k] = ((u32)(d & 255) << 21) | (u32)i;
      r_[k] = atomicAdd(&cnt[bb], 1);
    }
  }
  __syncthreads();
  int c0 = cnt[2 * t], c1 = cnt[2 * t + 1];
  tmp[t] = c0 + c1;
  __syncthreads();
  for (int off = 1; off < 256; off <<= 1) {
    int v = (t >= off) ? tmp[t - off] : 0;
    __syncthreads();
    tmp[t] += v;
    __syncthreads();
  }
  int excl = tmp[t] - (c0 + c1);
  bl[2 * t] = excl; bl[2 * t + 1] = excl + c0;
  __syncthreads();
#pragma unroll
  for (int k = 0; k < 16; ++k)
    if (b_[k] >= 0) st[bl[b_[k]] + r_[k]] = make_uint2(s_[k], y_[k]);
  for (int b = t; b < 512; b += 256) {
    int n = cnt[b];
    gb[b] = (n > 0) ? atomicAdd(&bcur[b], n) : 0;
  }
  __syncthreads();
  for (int b = t; b < 512; b += 256) {
    int n = cnt[b];
    if (n > 0) {
      uint2* dp = bstage + offs[b << 8] + gb[b];
      const uint2* sp = st + bl[b];
      for (int j = 0; j < n; ++j) dp[j] = sp[j];
    }
  }
}

// ---------------- final fill: one block per bucket, L2-local CSR window ----------------
__launch_bounds__(256)
__global__ void k_fillb(const uint2* __restrict__ bstage, const int* __restrict__ offs,
                        int* __restrict__ csr_src, int* __restrict__ csr_dst,
                        int* __restrict__ csr_eid) {
  __shared__ int curl[256];
  int t = threadIdx.x;
  int b = blockIdx.x;                  // 0..NBK-1
  int nb0 = b << 8;
  curl[t] = 0;
  __syncthreads();
  int sbase = offs[nb0];
  int send = (b == NBK - 1) ? NE : offs[nb0 + 256];
  for (int j = sbase + t; j < send; j += 256) {
    uint2 e = bstage[j];
    int dl = e.y >> 21;
    int eid = e.y & 0x1FFFFF;
    int pos = offs[nb0 + dl] + atomicAdd(&curl[dl], 1);
    csr_src[pos] = (int)e.x;
    csr_dst[pos] = nb0 + dl;
    csr_eid[pos] = eid;
  }
}

// ---------------- fp32 -> bf16 convert (for x) ----------------
__global__ void k_tobf(const float* __restrict__ in, u16* __restrict__ out, int n4) {
  int i = blockIdx.x * blockDim.x + threadIdx.x;
  if (i < n4) {
    float4 v = ((const float4*)in)[i];
    ushort4 o;
    o.x = f2bf(v.x); o.y = f2bf(v.y); o.z = f2bf(v.z); o.w = f2bf(v.w);
    ((ushort4*)out)[i] = o;
  }
}

// ---------------- pack all 3 W into MFMA B-frag order ----------------
__global__ void k_pack3(const float* __restrict__ W1, const float* __restrict__ W2,
                        const float* __restrict__ W3, u16* __restrict__ Wp1,
                        u16* __restrict__ Wp2, u16* __restrict__ Wp3) {
  int gid = blockIdx.x * blockDim.x + threadIdx.x;   // 3*16384
  int which = gid >> 14;
  int tid = gid & 16383;
  const float* W = which == 0 ? W1 : (which == 1 ? W2 : W3);
  u16* Wp = which == 0 ? Wp1 : (which == 1 ? Wp2 : Wp3);
  int b = tid & 7, j = (tid >> 3) & 15, kb = (tid >> 7) & 3, ks = (tid >> 9) & 3, ct = tid >> 11;
  int k = ks * 32 + kb * 8 + b, col = ct * 16 + j;
  Wp[tid] = f2bf(W[k * 128 + col]);
}

// ---------------- MFMA GEMM: hp[n] = bf16( dinv[n] * (Xb[n] @ W) ) ----------------
__launch_bounds__(256)
__global__ void k_gemm(const u16* __restrict__ Xb, const u16* __restrict__ Wp,
                       const float* __restrict__ dinv, u16* __restrict__ hp) {
  __shared__ u16 wl[16384];        // packed W, 32 KB
  __shared__ u16 ctile[4][2048];   // per-wave epilogue staging, 16 KB
  int t = threadIdx.x;
  int w = t >> 6, l = t & 63;
  int row0 = blockIdx.x * 64;
  int rbase = row0 + w * 16;

#pragma unroll
  for (int i = 0; i < 8; ++i) {
    int off = (i * 256 + t) * 8;
    *(uint4*)&wl[off] = *(const uint4*)&Wp[off];
  }
  __syncthreads();

  int arow = rbase + (l & 15);
  arow = arow < NN ? arow : NN - 1;
  const u16* abase = Xb + (size_t)arow * DIM + (l >> 4) * 8;
  bf16x8 a[4];
#pragma unroll
  for (int ks = 0; ks < 4; ++ks) a[ks] = *(const bf16x8*)(abase + ks * 32);

  f32x4 acc[8];
#pragma unroll
  for (int ct = 0; ct < 8; ++ct) {
    acc[ct] = (f32x4){0.f, 0.f, 0.f, 0.f};
#pragma unroll
    for (int ks = 0; ks < 4; ++ks) {
      bf16x8 bfr = *(const bf16x8*)&wl[ct * 2048 + ks * 512 + (l >> 4) * 128 + (l & 15) * 8];
      acc[ct] = __builtin_amdgcn_mfma_f32_16x16x32_bf16(a[ks], bfr, acc[ct], 0, 0, 0);
    }
  }

  float dv[4];
#pragma unroll
  for (int v = 0; v < 4; ++v) {
    int rr = rbase + (l >> 4) * 4 + v;
    dv[v] = dinv[rr < NN ? rr : NN - 1];
  }
  u16* ct_lds = ctile[w];
#pragma unroll
  for (int ct = 0; ct < 8; ++ct) {
#pragma unroll
    for (int v = 0; v < 4; ++v) {
      int row = (l >> 4) * 4 + v;
      ct_lds[row * DIM + ct * 16 + (l & 15)] = f2bf(dv[v] * acc[ct][v]);
    }
  }
  __syncthreads();
#pragma unroll
  for (int rr = 0; rr < 4; ++rr) {
    int row = rr * 4 + (l >> 4);
    int grow = rbase + row;
    if (grow < NN)
      *(uint4*)&hp[(size_t)grow * DIM + (l & 15) * 8] =
          *(const uint4*)&ct_lds[row * DIM + (l & 15) * 8];
  }
}

// ---------------- aggregation on bf16 h': out = bf16( dn*(sum h'[u] + h'[n]) + b ) ----
__launch_bounds__(256)
__global__ void k_agg(const u16* __restrict__ hp, const int* __restrict__ csr_src,
                      const int* __restrict__ offs, const int* __restrict__ deg,
                      const float* __restrict__ dinv, const float* __restrict__ bias,
                      u16* __restrict__ outb, int relu) {
  int t = threadIdx.x;
  int g = t >> 5, l = t & 31;
  int n = blockIdx.x * 8 + g;          // NN/8 exact
  float dn = dinv[n];
  int s = offs[n], cnt = deg[n];
  const uint2* hp2 = (const uint2*)hp;   // 4 bf16 per uint2, 32 per row
  float a0 = 0.f, a1 = 0.f, a2 = 0.f, a3 = 0.f;
  int i = 0;
  for (; i + 8 <= cnt; i += 8) {
    int u[8];
#pragma unroll
    for (int k = 0; k < 8; ++k) u[k] = csr_src[s + i + k];
    uint2 v[8];
#pragma unroll
    for (int k = 0; k < 8; ++k) v[k] = hp2[(size_t)u[k] * 32 + l];
#pragma unroll
    for (int k = 0; k < 8; ++k) {
      a0 += bflo(v[k].x); a1 += bfhi(v[k].x); a2 += bflo(v[k].y); a3 += bfhi(v[k].y);
    }
  }
  for (; i + 4 <= cnt; i += 4) {
    int u[4];
#pragma unroll
    for (int k = 0; k < 4; ++k) u[k] = csr_src[s + i + k];
    uint2 v[4];
#pragma unroll
    for (int k = 0; k < 4; ++k) v[k] = hp2[(size_t)u[k] * 32 + l];
#pragma unroll
    for (int k = 0; k < 4; ++k) {
      a0 += bflo(v[k].x); a1 += bfhi(v[k].x); a2 += bflo(v[k].y); a3 += bfhi(v[k].y);
    }
  }
  for (; i < cnt; ++i) {
    int u = csr_src[s + i];
    uint2 v = hp2[(size_t)u * 32 + l];
    a0 += bflo(v.x); a1 += bfhi(v.x); a2 += bflo(v.y); a3 += bfhi(v.y);
  }
  uint2 sv = hp2[(size_t)n * 32 + l];
  float4 bb = ((const float4*)bias)[l];
  float r0 = dn * (a0 + bflo(sv.x)) + bb.x;
  float r1 = dn * (a1 + bfhi(sv.x)) + bb.y;
  float r2 = dn * (a2 + bflo(sv.y)) + bb.z;
  float r3 = dn * (a3 + bfhi(sv.y)) + bb.w;
  if (relu) {
    r0 = fmaxf(r0, 0.f); r1 = fmaxf(r1, 0.f);
    r2 = fmaxf(r2, 0.f); r3 = fmaxf(r3, 0.f);
  }
  ushort4 o; o.x = f2bf(r0); o.y = f2bf(r1); o.z = f2bf(r2); o.w = f2bf(r3);
  *(ushort4*)&outb[(size_t)n * DIM + l * 4] = o;
}

// ---------------- MFMA decode: 16-edge tiles, dedup'd dst columns ----------------
// A[row=edge][k] = z[src_e]; B[k][col] = z[dstlist[col]]; result at D[e][col(e)].
__launch_bounds__(256)
__global__ void k_decode_mfma(const u16* __restrict__ z, const int* __restrict__ csr_src,
                              const int* __restrict__ csr_dst, const int* __restrict__ csr_eid,
                              float* __restrict__ out) {
  int l = threadIdx.x & 63;
  int wid = blockIdx.x * 4 + (threadIdx.x >> 6);
  int r = l & 15, g = l >> 4;          // r: A-row / B-col role; g: k-group
  int tile0 = wid * 8;                 // 8 tiles per wave; 100000 tiles total
  for (int tt = 0; tt < 8; ++tt) {
    int p0 = (tile0 + tt) * 16;        // NE divisible by 16, no tail
    int e = p0 + r;
    int s = csr_src[e];
    int d = csr_dst[e];
    // distinct-dst boundaries within the 16-edge tile
    int dprev = __shfl(d, (l & 48) | ((r - 1) & 15));
    unsigned long long bm = __ballot(r > 0 && d != dprev);
    u32 m16 = (u32)(bm >> (l & 48)) & 0xFFFFu;
    // this lane's B column c = r -> source row = position of r-th set bit
    u32 m = m16; int rc = 0;
    for (int j = 0; j < r; ++j) {
      if (!m) break;
      rc = __ffs(m) - 1;
      m &= m - 1;
    }
    int dget = __shfl(d, (l & 48) | rc);
    const bf16x8* za = (const bf16x8*)(z + (size_t)s * DIM + g * 8);
    const bf16x8* zc = (const bf16x8*)(z + (size_t)dget * DIM + g * 8);
    f32x4 acc = (f32x4){0.f, 0.f, 0.f, 0.f};
#pragma unroll
    for (int ks = 0; ks < 4; ++ks)
      acc = __builtin_amdgcn_mfma_f32_16x16x32_bf16(za[ks * 4], zc[ks * 4], acc, 0, 0, 0);
    // D[row=g*4+reg][col=r]: store where col(row)==r
#pragma unroll
    for (int reg = 0; reg < 4; ++reg) {
      int rr = g * 4 + reg;
      int colr = __popc(m16 & ((2u << rr) - 1));
      if (colr == r) out[csr_eid[p0 + rr]] = sigm(acc[reg]);
    }
  }
}

extern "C" void kernel_launch(void* const* d_in, const int* in_sizes, int n_in,
                              void* d_out, int out_size, void* d_ws, size_t ws_size,
                              hipStream_t stream) {
  const float* x  = (const float*)d_in[0];
  const float* W1 = (const float*)d_in[1];
  const float* b1 = (const float*)d_in[2];
  const float* W2 = (const float*)d_in[3];
  const float* b2 = (const float*)d_in[4];
  const float* W3 = (const float*)d_in[5];
  const float* b3 = (const float*)d_in[6];
  const int*   ei = (const int*)d_in[7];
  const int* src = ei;
  const int* dst = ei + NE;
  float* out = (float*)d_out;

  char* w = (char*)d_ws;
  size_t p = 0;
  auto alloc = [&](size_t bytes) -> void* {
    void* r = w + p;
    p += (bytes + 255) & ~(size_t)255;
    return r;
  };
  int*   deg     = (int*)alloc((size_t)NN * 4);
  int*   offs    = (int*)alloc((size_t)NN * 4);
  float* dinv    = (float*)alloc((size_t)NN * 4);
  int*   bsum    = (int*)alloc(1024);
  int*   bcur    = (int*)alloc(512 * 4);
  uint2* bstage  = (uint2*)alloc((size_t)NE * 8);       // bucketed staging
  int*   csr_src = (int*)alloc((size_t)NE * 4);
  int*   csr_dst = (int*)alloc((size_t)NE * 4);
  int*   csr_eid = (int*)alloc((size_t)NE * 4);
  u16*   Xb      = (u16*)alloc((size_t)NN * DIM * 2);   // bf16 input features
  u16*   hp      = (u16*)alloc((size_t)NN * DIM * 2);   // bf16 GEMM out (premult by dinv)
  u16*   hb      = (u16*)alloc((size_t)NN * DIM * 2);   // bf16 agg out (next GEMM input / z)
  u16*   Wp1     = (u16*)alloc(16384 * 2);
  u16*   Wp2     = (u16*)alloc(16384 * 2);
  u16*   Wp3     = (u16*)alloc(16384 * 2);
  (void)in_sizes; (void)n_in; (void)out_size; (void)ws_size;

  hipMemsetAsync(deg, 0, (size_t)NN * 4, stream);
  hipMemsetAsync(bcur, 0, 512 * 4, stream);

  k_deg<<<(NE + 255) / 256, 256, 0, stream>>>(dst, deg);
  int nb = (NN + SCHUNK - 1) / SCHUNK;  // 98
  k_scan1<<<nb, 256, 0, stream>>>(deg, bsum);
  k_scan2<<<1, 128, 0, stream>>>(bsum, nb);
  k_scan3<<<nb, 256, 0, stream>>>(deg, bsum, offs, dinv);

  int cb = (NE + ECH - 1) / ECH;  // 391
  k_bucket<<<cb, 256, 0, stream>>>(src, dst, offs, bcur, bstage);
  k_fillb<<<NBK, 256, 0, stream>>>(bstage, offs, csr_src, csr_dst, csr_eid);

  k_tobf<<<(NN * DIM / 4 + 255) / 256, 256, 0, stream>>>(x, Xb, NN * DIM / 4);
  k_pack3<<<192, 256, 0, stream>>>(W1, W2, W3, Wp1, Wp2, Wp3);

  int gb = (NN + 63) / 64;  // 1563
  k_gemm<<<gb, 256, 0, stream>>>(Xb, Wp1, dinv, hp);
  k_agg <<<NN / 8, 256, 0, stream>>>(hp, csr_src, offs, deg, dinv, b1, hb, 1);
  k_gemm<<<gb, 256, 0, stream>>>(hb, Wp2, dinv, hp);
  k_agg <<<NN / 8, 256, 0, stream>>>(hp, csr_src, offs, deg, dinv, b2, hb, 1);
  k_gemm<<<gb, 256, 0, stream>>>(hb, Wp3, dinv, hp);
  k_agg <<<NN / 8, 256, 0, stream>>>(hp, csr_src, offs, deg, dinv, b3, hb, 0);

  // 100000 tiles / (4 waves * 8 tiles) = 3125 blocks
  k_decode_mfma<<<3125, 256, 0, stream>>>(hb, csr_src, csr_dst, csr_eid, out);
}